// Round 9
// baseline (178.983 us; speedup 1.0000x reference)
//
#include <hip/hip_runtime.h>
#include <math.h>

// Problem constants
#define Bv 2
#define Tv 2048
#define Cv 1024
#define Hv 16
#define HDv 64
#define Mv (Bv * Tv)             // 4096 rows
#define SZv (Bv * Hv * Tv * HDv) // 4,194,304 elements per Q/K/V section

typedef short bf16x8 __attribute__((ext_vector_type(8)));
typedef float f32x4 __attribute__((ext_vector_type(4)));

static __device__ __forceinline__ unsigned short f2bf(float f) {
    unsigned u = __float_as_uint(f);
    u += 0x7fffu + ((u >> 16) & 1u);
    return (unsigned short)(u >> 16);
}

// Packed fp32x2 -> bf16x2 (RNE), single HW instr on gfx950.
static __device__ __forceinline__ unsigned f2bf2(float a, float b) {
    unsigned r;
    asm("v_cvt_pk_bf16_f32 %0, %1, %2" : "=v"(r) : "v"(a), "v"(b));
    return r;
}

#define AS1 __attribute__((address_space(1)))
#define AS3 __attribute__((address_space(3)))
// 16B-per-lane async global->LDS: LDS dest = wave-uniform base + lane*16.
#define GLD16(gp, lp) __builtin_amdgcn_global_load_lds( \
    (AS1 const void*)(const void*)(gp), (AS3 void*)(void*)(lp), 16, 0, 0)

#define WAITVM(n) asm volatile("s_waitcnt vmcnt(" #n ")" ::: "memory")
#define WAITLGKM0 asm volatile("s_waitcnt lgkmcnt(0)" ::: "memory")
#define BARRIER   asm volatile("s_barrier" ::: "memory")

// ---------------------------------------------------------------------------
// Prep: fused x fp32->bf16 convert + W_attn/W_proj transpose-to-bf16.
// Grid partition: [0,4096) cvt, [4096,7168) W_attn^T, [7168,8192) W_proj^T.
// ---------------------------------------------------------------------------
__global__ __launch_bounds__(256) void prep_kernel(
    const float* __restrict__ x, const float* __restrict__ Wa,
    const float* __restrict__ Wp,
    unsigned short* __restrict__ xB, unsigned short* __restrict__ WaT,
    unsigned short* __restrict__ WpT)
{
    __shared__ float tile[32][33];
    const int bid = blockIdx.x;
    const int tid = threadIdx.x;

    if (bid < 4096) {               // cvt x: 1,048,576 float4 groups
        int i = bid * 256 + tid;
        float4 f = ((const float4*)x)[i];
        ushort4 u;
        u.x = f2bf(f.x); u.y = f2bf(f.y); u.z = f2bf(f.z); u.w = f2bf(f.w);
        ((ushort4*)xB)[i] = u;
        return;
    }
    const float* src; unsigned short* dst; int Ncols, bi;
    if (bid < 7168) { bi = bid - 4096; Ncols = 3072; src = Wa; dst = WaT; }
    else            { bi = bid - 7168; Ncols = 1024; src = Wp; dst = WpT; }
    const int nct = Ncols / 32;
    const int c0 = (bi % nct) * 32, r0 = (bi / nct) * 32;
    const int tx = tid & 31, ty = tid >> 5;  // ty 0..7
    #pragma unroll
    for (int i = 0; i < 4; ++i)
        tile[ty + i * 8][tx] = src[(size_t)(r0 + ty + i * 8) * Ncols + c0 + tx];
    __syncthreads();
    #pragma unroll
    for (int i = 0; i < 4; ++i)
        dst[(size_t)(c0 + ty + i * 8) * Cv + r0 + tx] = f2bf(tile[tx][ty + i * 8]);
}

// ---------------------------------------------------------------------------
// Shared 128x128 bf16 MFMA GEMM mainloop, K=1024. Triple-buffered staging,
// one barrier per iter, prefetch distance 2, vmcnt(4).
// lds must hold 24576 shorts (48 KB): buf k at offset k*8192.
// ---------------------------------------------------------------------------
__device__ __forceinline__ void mm_mainloop_1024(
    const unsigned short* __restrict__ A, const unsigned short* __restrict__ Bt,
    unsigned short* lds, int rowBase, int colBase, f32x4 acc[4][4])
{
    const int tid  = threadIdx.x;
    const int lane = tid & 63;
    const int w    = tid >> 6;
    const int quad = lane >> 4, l15 = lane & 15;
    const int wm = (w >> 1) * 64, wn = (w & 1) * 64;
    const int K = 1024;

    const int g0 = (w * 2 + 0) * 64 + lane;
    const int g1 = (w * 2 + 1) * 64 + lane;
    const int r0 = g0 >> 2, r1 = g1 >> 2;
    const int kc0 = (g0 & 3) ^ ((r0 >> 1) & 3);
    const int kc1 = (g1 & 3) ^ ((r1 >> 1) & 3);
    const size_t offA0 = (size_t)(rowBase + r0) * K + kc0 * 8;
    const size_t offA1 = (size_t)(rowBase + r1) * K + kc1 * 8;
    const size_t offB0 = (size_t)(colBase + r0) * K + kc0 * 8;
    const size_t offB1 = (size_t)(colBase + r1) * K + kc1 * 8;
    unsigned short* ldsA0 = lds + (w * 2 + 0) * 512;
    unsigned short* ldsA1 = lds + (w * 2 + 1) * 512;
    unsigned short* ldsB0 = lds + 4096 + (w * 2 + 0) * 512;
    unsigned short* ldsB1 = lds + 4096 + (w * 2 + 1) * 512;

    const int sw = quad ^ ((l15 >> 1) & 3);
    int aoff[4], boff[4];
    #pragma unroll
    for (int i = 0; i < 4; ++i) {
        aoff[i] = ((wm + i * 16 + l15) * 4 + sw) * 8;
        boff[i] = 4096 + ((wn + i * 16 + l15) * 4 + sw) * 8;
    }

    // Prologue: tiles 0,1 into bufs 0,1.
    GLD16(A + offA0, ldsA0);
    GLD16(A + offA1, ldsA1);
    GLD16(Bt + offB0, ldsB0);
    GLD16(Bt + offB1, ldsB1);
    GLD16(A + offA0 + 32, ldsA0 + 8192);
    GLD16(A + offA1 + 32, ldsA1 + 8192);
    GLD16(Bt + offB0 + 32, ldsB0 + 8192);
    GLD16(Bt + offB1 + 32, ldsB1 + 8192);

    int cur = 0;
    for (int i = 0; i < 32; ++i) {
        if (i < 31) { WAITVM(4); } else { WAITVM(0); }
        BARRIER;
        if (i < 30) {
            int nb = cur + 16384; if (nb >= 24576) nb -= 24576;
            const int k2 = (i + 2) * 32;
            GLD16(A + offA0 + k2, ldsA0 + nb);
            GLD16(A + offA1 + k2, ldsA1 + nb);
            GLD16(Bt + offB0 + k2, ldsB0 + nb);
            GLD16(Bt + offB1 + k2, ldsB1 + nb);
        }

        bf16x8 a[4], b[4];
        #pragma unroll
        for (int j = 0; j < 4; ++j) a[j] = *(const bf16x8*)(lds + cur + aoff[j]);
        #pragma unroll
        for (int j = 0; j < 4; ++j) b[j] = *(const bf16x8*)(lds + cur + boff[j]);

        #pragma unroll
        for (int mi = 0; mi < 4; ++mi)
            #pragma unroll
            for (int ni = 0; ni < 4; ++ni)
                acc[mi][ni] = __builtin_amdgcn_mfma_f32_16x16x32_bf16(
                    a[mi], b[ni], acc[mi][ni], 0, 0, 0);

        cur += 8192; if (cur == 24576) cur = 0;
    }
}

// ---------------------------------------------------------------------------
// QKV GEMM: bf16 MFMA; epilogue scatters Q,K [bh][t][d], V^T [bh][d][t].
// Q is pre-scaled by log2(e)/32 so attention's softmax is a bare exp2.
// ---------------------------------------------------------------------------
__global__ __launch_bounds__(256) void qkv_mm_kernel(
    const unsigned short* __restrict__ xB, const unsigned short* __restrict__ WaT,
    const float* __restrict__ bias,
    unsigned short* __restrict__ qB, unsigned short* __restrict__ kB,
    unsigned short* __restrict__ vT)
{
    __shared__ __align__(16) unsigned short lds[24576];
    const int rowBase = blockIdx.y * 128;
    const int colBase = blockIdx.x * 128;

    f32x4 acc[4][4];
    #pragma unroll
    for (int i = 0; i < 4; ++i)
        #pragma unroll
        for (int j = 0; j < 4; ++j) acc[i][j] = (f32x4){0.f, 0.f, 0.f, 0.f};

    mm_mainloop_1024(xB, WaT, lds, rowBase, colBase, acc);
    __syncthreads();

    const int tid = threadIdx.x, lane = tid & 63, w = tid >> 6;
    const int quad = lane >> 4, l15 = lane & 15;
    const int wm = (w >> 1) * 64, wn = (w & 1) * 64;
    const int s = colBase / Cv;                       // 0=q,1=k,2=v (uniform)
    const int tloc = rowBase & (Tv - 1);
    const int bh0 = (rowBase / Tv) * Hv + (colBase % Cv) / HDv;

    if (s < 2) {
        const float qs = (s == 0) ? 0.04508422f : 1.0f;  // log2(e)/32
        #pragma unroll
        for (int mi = 0; mi < 4; ++mi)
            #pragma unroll
            for (int ni = 0; ni < 4; ++ni) {
                float bv = bias[colBase + wn + ni * 16 + l15];
                #pragma unroll
                for (int r = 0; r < 4; ++r) {
                    int m = wm + mi * 16 + quad * 4 + r;
                    int n = wn + ni * 16 + l15;
                    lds[m * 136 + n] = f2bf((acc[mi][ni][r] + bv) * qs);
                }
            }
        __syncthreads();
        unsigned short* dst = (s == 0) ? qB : kB;
        #pragma unroll
        for (int it = 0; it < 8; ++it) {
            int cc = tid + it * 256;
            int m = cc >> 4, j = cc & 15;
            uint4 v = *(const uint4*)(lds + m * 136 + j * 8);
            int hh = j >> 3, d0 = (j & 7) * 8;
            *(uint4*)(dst + ((size_t)(bh0 + hh) * Tv + tloc + m) * HDv + d0) = v;
        }
    } else {
        #pragma unroll
        for (int mi = 0; mi < 4; ++mi)
            #pragma unroll
            for (int ni = 0; ni < 4; ++ni) {
                float bv = bias[colBase + wn + ni * 16 + l15];
                #pragma unroll
                for (int r = 0; r < 4; ++r) {
                    int m = wm + mi * 16 + quad * 4 + r;
                    int n = wn + ni * 16 + l15;
                    lds[n * 136 + m] = f2bf(acc[mi][ni][r] + bv);
                }
            }
        __syncthreads();
        #pragma unroll
        for (int it = 0; it < 8; ++it) {
            int cc = tid + it * 256;
            int n = cc >> 4, j = cc & 15;
            uint4 v = *(const uint4*)(lds + n * 136 + j * 8);
            int hh = n >> 6, d = n & 63;
            *(uint4*)(vT + ((size_t)(bh0 + hh) * HDv + d) * Tv + tloc + j * 8) = v;
        }
    }
}

// ---------------------------------------------------------------------------
// Projection GEMM: bf16 MFMA, fp32 output + bias.
// ---------------------------------------------------------------------------
__global__ __launch_bounds__(256) void proj_mm_kernel(
    const unsigned short* __restrict__ y0B, const unsigned short* __restrict__ WpT,
    const float* __restrict__ bias, float* __restrict__ out)
{
    __shared__ __align__(16) unsigned short lds[24576];  // 48 KB staging
    const int rowBase = blockIdx.y * 128;
    const int colBase = blockIdx.x * 128;

    f32x4 acc[4][4];
    #pragma unroll
    for (int i = 0; i < 4; ++i)
        #pragma unroll
        for (int j = 0; j < 4; ++j) acc[i][j] = (f32x4){0.f, 0.f, 0.f, 0.f};

    mm_mainloop_1024(y0B, WpT, lds, rowBase, colBase, acc);

    const int tid = threadIdx.x, lane = tid & 63, w = tid >> 6;
    const int quad = lane >> 4, l15 = lane & 15;
    const int wm = (w >> 1) * 64, wn = (w & 1) * 64;

    #pragma unroll
    for (int mi = 0; mi < 4; ++mi)
        #pragma unroll
        for (int ni = 0; ni < 4; ++ni) {
            int n = colBase + wn + ni * 16 + l15;
            float bv = bias[n];
            #pragma unroll
            for (int r = 0; r < 4; ++r) {
                int m = rowBase + wm + mi * 16 + quad * 4 + r;
                out[(size_t)m * Cv + n] = acc[mi][ni][r] + bv;
            }
        }
}

// ---------------------------------------------------------------------------
// Causal attention. R8: block = 128 query rows (wave = two 16-row subtiles),
// 64-key LDS-staged tiles shared by all 4 waves, dbuf + one barrier/iter.
// Same staged tile feeds 2x MFMA work vs R7: block-iters 16896->8704,
// staged bytes and barriers halved, two independent S/PV chains per iter.
// No-online-softmax (scores bounded, shift-invariant softmax exact).
// Q pre-scaled by log2(e)/32 -> bare v_exp_f32.
// ---------------------------------------------------------------------------
__global__ __launch_bounds__(256) void attn_kernel(
    const unsigned short* __restrict__ qB, const unsigned short* __restrict__ kB,
    const unsigned short* __restrict__ vT, unsigned short* __restrict__ y0B)
{
    // Per buffer (8192 shorts): K tile [0,4096), V tile [4096,8192).
    __shared__ __align__(16) unsigned short kv[2 * 8192];     // 32 KB
    __shared__ __align__(16) unsigned short Pb[4][32 * 72];   // 18 KB

    const int tid  = threadIdx.x;
    const int lane = tid & 63;
    const int w    = tid >> 6;
    const int quad = lane >> 4;
    const int l15  = lane & 15;

    const int qt = 15 - (blockIdx.x >> 5);   // heavy tiles dispatch first
    const int bh = blockIdx.x & 31;
    const int qbase = qt * 128 + w * 32;     // wave's 32 query rows

    // Q fragments: subtile s rows qbase+s*16+l15, chunks d 0..31 / 32..63
    bf16x8 Qa[2][2];
    #pragma unroll
    for (int s = 0; s < 2; ++s) {
        const unsigned short* qrow = qB + ((size_t)bh * Tv + qbase + s * 16 + l15) * HDv;
        Qa[s][0] = *(const bf16x8*)(qrow + quad * 8);
        Qa[s][1] = *(const bf16x8*)(qrow + 32 + quad * 8);
    }
    WAITVM(0);   // Q in regs; loop-local vmcnt tracks only staging GLDs

    f32x4 O[2][4];
    float l[2][4];
    #pragma unroll
    for (int s = 0; s < 2; ++s)
        #pragma unroll
        for (int n = 0; n < 4; ++n) { O[s][n] = (f32x4){0.f, 0.f, 0.f, 0.f}; l[s][n] = 0.f; }

    const unsigned short* Kbase = kB + (size_t)bh * Tv * HDv;
    const unsigned short* Vbase = vT + (size_t)bh * HDv * Tv;
    unsigned short* Pw = &Pb[w][0];

    // Staging: thread covers 4 granule-slots/tile: K slots tid+{0,256},
    // V slots tid+{0,256}. Swizzles: K g^((row>>2)&7), V g^(d&7).
    const unsigned short* gK[2]; unsigned short* dK[2];
    const unsigned short* gV[2]; unsigned short* dV[2];
    #pragma unroll
    for (int i = 0; i < 2; ++i) {
        int slot = tid + i * 256;
        int row = slot >> 3;
        int gk = (slot & 7) ^ ((row >> 2) & 7);
        gK[i] = Kbase + row * HDv + gk * 8;
        dK[i] = kv + (size_t)(i * 256 + w * 64) * 8;
        int d = slot >> 3;
        int gv = (slot & 7) ^ (d & 7);
        gV[i] = Vbase + (size_t)d * Tv + gv * 8;
        dV[i] = kv + 4096 + (size_t)(i * 256 + w * 64) * 8;
    }

    // Fragment LDS short-offsets (constant across kt; add buffer offset).
    int koff[4][2], voff[4][2];
    #pragma unroll
    for (int ct = 0; ct < 4; ++ct) {
        int row = ct + 4 * l15;
        #pragma unroll
        for (int j = 0; j < 2; ++j)
            koff[ct][j] = (row * 8 + ((quad + 4 * j) ^ (l15 & 7))) * 8;
    }
    #pragma unroll
    for (int nt = 0; nt < 4; ++nt) {
        int d = nt * 16 + l15;
        #pragma unroll
        for (int j = 0; j < 2; ++j)
            voff[nt][j] = 4096 + (d * 8 + ((quad + 4 * j) ^ (l15 & 7))) * 8;
    }

    const int numT = 2 * qt + 2;             // 64-key tiles (causal)

    // Prologue: tile 0 into buf0.
    GLD16(gK[0], dK[0]);
    GLD16(gK[1], dK[1]);
    GLD16(gV[0], dV[0]);
    GLD16(gV[1], dV[1]);

    int cur = 0;
    for (int kt = 0; kt < numT; ++kt) {
        WAITVM(0);
        BARRIER;
        if (kt + 1 < numT) {
            const int kb1 = (kt + 1) * 64;
            const int nxt = 8192 - cur;
            GLD16(gK[0] + (size_t)kb1 * HDv, dK[0] + nxt);
            GLD16(gK[1] + (size_t)kb1 * HDv, dK[1] + nxt);
            GLD16(gV[0] + kb1, dV[0] + nxt);
            GLD16(gV[1] + kb1, dV[1] + nxt);
        }

        bf16x8 Kb[4][2], Vb[4][2];
        #pragma unroll
        for (int ct = 0; ct < 4; ++ct) {
            Kb[ct][0] = *(const bf16x8*)(kv + cur + koff[ct][0]);
            Kb[ct][1] = *(const bf16x8*)(kv + cur + koff[ct][1]);
        }
        #pragma unroll
        for (int nt = 0; nt < 4; ++nt) {
            Vb[nt][0] = *(const bf16x8*)(kv + cur + voff[nt][0]);
            Vb[nt][1] = *(const bf16x8*)(kv + cur + voff[nt][1]);
        }

        f32x4 S[2][4];
        #pragma unroll
        for (int s = 0; s < 2; ++s)
            #pragma unroll
            for (int ct = 0; ct < 4; ++ct) {
                S[s][ct] = (f32x4){0.f, 0.f, 0.f, 0.f};
                S[s][ct] = __builtin_amdgcn_mfma_f32_16x16x32_bf16(Qa[s][0], Kb[ct][0], S[s][ct], 0, 0, 0);
                S[s][ct] = __builtin_amdgcn_mfma_f32_16x16x32_bf16(Qa[s][1], Kb[ct][1], S[s][ct], 0, 0, 0);
            }

        if (kt >= numT - 2) {  // only last two tiles can cross the diagonal
            const int kb = kt * 64;
            #pragma unroll
            for (int s = 0; s < 2; ++s)
                #pragma unroll
                for (int ct = 0; ct < 4; ++ct)
                    #pragma unroll
                    for (int r = 0; r < 4; ++r)
                        if (kb + ct + 4 * l15 > qbase + s * 16 + quad * 4 + r)
                            S[s][ct][r] = -1e30f;
        }

        float p[2][4][4];
        #pragma unroll
        for (int s = 0; s < 2; ++s) {
            #pragma unroll
            for (int ct = 0; ct < 4; ++ct)
                #pragma unroll
                for (int r = 0; r < 4; ++r)
                    p[s][ct][r] = __builtin_amdgcn_exp2f(S[s][ct][r]);
            #pragma unroll
            for (int r = 0; r < 4; ++r)
                l[s][r] += (p[s][0][r] + p[s][1][r]) + (p[s][2][r] + p[s][3][r]);
        }

        // P pack: keys 4*l15+ct adjacent -> one 8B LDS write per row
        #pragma unroll
        for (int s = 0; s < 2; ++s)
            #pragma unroll
            for (int r = 0; r < 4; ++r) {
                uint2 u = make_uint2(f2bf2(p[s][0][r], p[s][1][r]),
                                     f2bf2(p[s][2][r], p[s][3][r]));
                *(uint2*)(Pw + (s * 16 + quad * 4 + r) * 72 + l15 * 4) = u;
            }
        WAITLGKM0;
        #pragma unroll
        for (int s = 0; s < 2; ++s) {
            const bf16x8 Pa0 = *(const bf16x8*)(Pw + (s * 16 + l15) * 72 + quad * 8);
            const bf16x8 Pa1 = *(const bf16x8*)(Pw + (s * 16 + l15) * 72 + 32 + quad * 8);
            #pragma unroll
            for (int nt = 0; nt < 4; ++nt) {
                O[s][nt] = __builtin_amdgcn_mfma_f32_16x16x32_bf16(Pa0, Vb[nt][0], O[s][nt], 0, 0, 0);
                O[s][nt] = __builtin_amdgcn_mfma_f32_16x16x32_bf16(Pa1, Vb[nt][1], O[s][nt], 0, 0, 0);
            }
        }

        cur = 8192 - cur;
    }

    // One-time row-sum reduce across the 16 lanes holding each row's keys
    #pragma unroll
    for (int s = 0; s < 2; ++s)
        #pragma unroll
        for (int r = 0; r < 4; ++r) {
            l[s][r] += __shfl_xor(l[s][r], 1);
            l[s][r] += __shfl_xor(l[s][r], 2);
            l[s][r] += __shfl_xor(l[s][r], 4);
            l[s][r] += __shfl_xor(l[s][r], 8);
        }

    const int b = bh >> 4, h = bh & 15;
    #pragma unroll
    for (int s = 0; s < 2; ++s)
        #pragma unroll
        for (int r = 0; r < 4; ++r) {
            float inv = 1.f / l[s][r];
            int q = qbase + s * 16 + quad * 4 + r;
            unsigned short* dst = y0B + ((size_t)(b * Tv + q)) * Cv + h * HDv + l15;
            #pragma unroll
            for (int n = 0; n < 4; ++n) dst[n * 16] = f2bf(O[s][n][r] * inv);
        }
}

// ---------------------------------------------------------------------------
// Workspace: xB 8MB | WaT 6MB | WpT 2MB | qB,kB,vT 24MB | y0B 8MB (~48 MB).
// ---------------------------------------------------------------------------
extern "C" void kernel_launch(void* const* d_in, const int* in_sizes, int n_in,
                              void* d_out, int out_size, void* d_ws, size_t ws_size,
                              hipStream_t stream) {
    const float* x      = (const float*)d_in[0];
    const float* W_attn = (const float*)d_in[1];
    const float* b_attn = (const float*)d_in[2];
    const float* W_proj = (const float*)d_in[3];
    const float* b_proj = (const float*)d_in[4];
    float* out = (float*)d_out;

    unsigned short* xB  = (unsigned short*)d_ws;
    unsigned short* WaT = xB  + (size_t)Mv * Cv;
    unsigned short* WpT = WaT + (size_t)3 * Cv * Cv;
    unsigned short* qB  = WpT + (size_t)Cv * Cv;
    unsigned short* kB  = qB + (size_t)SZv;
    unsigned short* vT  = kB + (size_t)SZv;
    unsigned short* y0B = vT + (size_t)SZv;

    dim3 blk(256);
    prep_kernel<<<dim3(8192), blk, 0, stream>>>(x, W_attn, W_proj, xB, WaT, WpT);
    qkv_mm_kernel<<<dim3(3 * Cv / 128, Mv / 128), blk, 0, stream>>>(xB, WaT, b_attn, qB, kB, vT);
    attn_kernel<<<dim3(Bv * Hv * (Tv / 128)), blk, 0, stream>>>(qB, kB, vT, y0B);
    proj_mm_kernel<<<dim3(Cv / 128, Mv / 128), blk, 0, stream>>>(y0B, WpT, b_proj, out);
}

// Round 10
// 163.632 us; speedup vs baseline: 1.0938x; 1.0938x over previous
//
#include <hip/hip_runtime.h>
#include <math.h>

// Problem constants
#define Bv 2
#define Tv 2048
#define Cv 1024
#define Hv 16
#define HDv 64
#define Mv (Bv * Tv)             // 4096 rows
#define SZv (Bv * Hv * Tv * HDv) // 4,194,304 elements per Q/K/V section

typedef short bf16x8 __attribute__((ext_vector_type(8)));
typedef float f32x4 __attribute__((ext_vector_type(4)));

static __device__ __forceinline__ unsigned short f2bf(float f) {
    unsigned u = __float_as_uint(f);
    u += 0x7fffu + ((u >> 16) & 1u);
    return (unsigned short)(u >> 16);
}

// Packed fp32x2 -> bf16x2 (RNE), single HW instr on gfx950.
static __device__ __forceinline__ unsigned f2bf2(float a, float b) {
    unsigned r;
    asm("v_cvt_pk_bf16_f32 %0, %1, %2" : "=v"(r) : "v"(a), "v"(b));
    return r;
}

#define AS1 __attribute__((address_space(1)))
#define AS3 __attribute__((address_space(3)))
// 16B-per-lane async global->LDS: LDS dest = wave-uniform base + lane*16.
#define GLD16(gp, lp) __builtin_amdgcn_global_load_lds( \
    (AS1 const void*)(const void*)(gp), (AS3 void*)(void*)(lp), 16, 0, 0)

#define WAITVM(n) asm volatile("s_waitcnt vmcnt(" #n ")" ::: "memory")
#define WAITLGKM0 asm volatile("s_waitcnt lgkmcnt(0)" ::: "memory")
#define BARRIER   asm volatile("s_barrier" ::: "memory")

// ---------------------------------------------------------------------------
// Prep: fused x fp32->bf16 convert + W_attn/W_proj transpose-to-bf16.
// Grid partition: [0,4096) cvt, [4096,7168) W_attn^T, [7168,8192) W_proj^T.
// ---------------------------------------------------------------------------
__global__ __launch_bounds__(256) void prep_kernel(
    const float* __restrict__ x, const float* __restrict__ Wa,
    const float* __restrict__ Wp,
    unsigned short* __restrict__ xB, unsigned short* __restrict__ WaT,
    unsigned short* __restrict__ WpT)
{
    __shared__ float tile[32][33];
    const int bid = blockIdx.x;
    const int tid = threadIdx.x;

    if (bid < 4096) {               // cvt x: 1,048,576 float4 groups
        int i = bid * 256 + tid;
        float4 f = ((const float4*)x)[i];
        ushort4 u;
        u.x = f2bf(f.x); u.y = f2bf(f.y); u.z = f2bf(f.z); u.w = f2bf(f.w);
        ((ushort4*)xB)[i] = u;
        return;
    }
    const float* src; unsigned short* dst; int Ncols, bi;
    if (bid < 7168) { bi = bid - 4096; Ncols = 3072; src = Wa; dst = WaT; }
    else            { bi = bid - 7168; Ncols = 1024; src = Wp; dst = WpT; }
    const int nct = Ncols / 32;
    const int c0 = (bi % nct) * 32, r0 = (bi / nct) * 32;
    const int tx = tid & 31, ty = tid >> 5;  // ty 0..7
    #pragma unroll
    for (int i = 0; i < 4; ++i)
        tile[ty + i * 8][tx] = src[(size_t)(r0 + ty + i * 8) * Ncols + c0 + tx];
    __syncthreads();
    #pragma unroll
    for (int i = 0; i < 4; ++i)
        dst[(size_t)(c0 + ty + i * 8) * Cv + r0 + tx] = f2bf(tile[tx][ty + i * 8]);
}

// ---------------------------------------------------------------------------
// Shared 128x128 bf16 MFMA GEMM mainloop, K=1024. Triple-buffered staging,
// one barrier per iter, prefetch distance 2, vmcnt(4).
// lds must hold 24576 shorts (48 KB): buf k at offset k*8192.
// ---------------------------------------------------------------------------
__device__ __forceinline__ void mm_mainloop_1024(
    const unsigned short* __restrict__ A, const unsigned short* __restrict__ Bt,
    unsigned short* lds, int rowBase, int colBase, f32x4 acc[4][4])
{
    const int tid  = threadIdx.x;
    const int lane = tid & 63;
    const int w    = tid >> 6;
    const int quad = lane >> 4, l15 = lane & 15;
    const int wm = (w >> 1) * 64, wn = (w & 1) * 64;
    const int K = 1024;

    const int g0 = (w * 2 + 0) * 64 + lane;
    const int g1 = (w * 2 + 1) * 64 + lane;
    const int r0 = g0 >> 2, r1 = g1 >> 2;
    const int kc0 = (g0 & 3) ^ ((r0 >> 1) & 3);
    const int kc1 = (g1 & 3) ^ ((r1 >> 1) & 3);
    const size_t offA0 = (size_t)(rowBase + r0) * K + kc0 * 8;
    const size_t offA1 = (size_t)(rowBase + r1) * K + kc1 * 8;
    const size_t offB0 = (size_t)(colBase + r0) * K + kc0 * 8;
    const size_t offB1 = (size_t)(colBase + r1) * K + kc1 * 8;
    unsigned short* ldsA0 = lds + (w * 2 + 0) * 512;
    unsigned short* ldsA1 = lds + (w * 2 + 1) * 512;
    unsigned short* ldsB0 = lds + 4096 + (w * 2 + 0) * 512;
    unsigned short* ldsB1 = lds + 4096 + (w * 2 + 1) * 512;

    const int sw = quad ^ ((l15 >> 1) & 3);
    int aoff[4], boff[4];
    #pragma unroll
    for (int i = 0; i < 4; ++i) {
        aoff[i] = ((wm + i * 16 + l15) * 4 + sw) * 8;
        boff[i] = 4096 + ((wn + i * 16 + l15) * 4 + sw) * 8;
    }

    // Prologue: tiles 0,1 into bufs 0,1.
    GLD16(A + offA0, ldsA0);
    GLD16(A + offA1, ldsA1);
    GLD16(Bt + offB0, ldsB0);
    GLD16(Bt + offB1, ldsB1);
    GLD16(A + offA0 + 32, ldsA0 + 8192);
    GLD16(A + offA1 + 32, ldsA1 + 8192);
    GLD16(Bt + offB0 + 32, ldsB0 + 8192);
    GLD16(Bt + offB1 + 32, ldsB1 + 8192);

    int cur = 0;
    for (int i = 0; i < 32; ++i) {
        if (i < 31) { WAITVM(4); } else { WAITVM(0); }
        BARRIER;
        if (i < 30) {
            int nb = cur + 16384; if (nb >= 24576) nb -= 24576;
            const int k2 = (i + 2) * 32;
            GLD16(A + offA0 + k2, ldsA0 + nb);
            GLD16(A + offA1 + k2, ldsA1 + nb);
            GLD16(Bt + offB0 + k2, ldsB0 + nb);
            GLD16(Bt + offB1 + k2, ldsB1 + nb);
        }

        bf16x8 a[4], b[4];
        #pragma unroll
        for (int j = 0; j < 4; ++j) a[j] = *(const bf16x8*)(lds + cur + aoff[j]);
        #pragma unroll
        for (int j = 0; j < 4; ++j) b[j] = *(const bf16x8*)(lds + cur + boff[j]);

        #pragma unroll
        for (int mi = 0; mi < 4; ++mi)
            #pragma unroll
            for (int ni = 0; ni < 4; ++ni)
                acc[mi][ni] = __builtin_amdgcn_mfma_f32_16x16x32_bf16(
                    a[mi], b[ni], acc[mi][ni], 0, 0, 0);

        cur += 8192; if (cur == 24576) cur = 0;
    }
}

// ---------------------------------------------------------------------------
// QKV GEMM: bf16 MFMA; epilogue scatters Q,K [bh][t][d], V^T [bh][d][t].
// Q is pre-scaled by log2(e)/32 so attention's softmax is a bare exp2.
// ---------------------------------------------------------------------------
__global__ __launch_bounds__(256) void qkv_mm_kernel(
    const unsigned short* __restrict__ xB, const unsigned short* __restrict__ WaT,
    const float* __restrict__ bias,
    unsigned short* __restrict__ qB, unsigned short* __restrict__ kB,
    unsigned short* __restrict__ vT)
{
    __shared__ __align__(16) unsigned short lds[24576];
    const int rowBase = blockIdx.y * 128;
    const int colBase = blockIdx.x * 128;

    f32x4 acc[4][4];
    #pragma unroll
    for (int i = 0; i < 4; ++i)
        #pragma unroll
        for (int j = 0; j < 4; ++j) acc[i][j] = (f32x4){0.f, 0.f, 0.f, 0.f};

    mm_mainloop_1024(xB, WaT, lds, rowBase, colBase, acc);
    __syncthreads();

    const int tid = threadIdx.x, lane = tid & 63, w = tid >> 6;
    const int quad = lane >> 4, l15 = lane & 15;
    const int wm = (w >> 1) * 64, wn = (w & 1) * 64;
    const int s = colBase / Cv;                       // 0=q,1=k,2=v (uniform)
    const int tloc = rowBase & (Tv - 1);
    const int bh0 = (rowBase / Tv) * Hv + (colBase % Cv) / HDv;

    if (s < 2) {
        const float qs = (s == 0) ? 0.04508422f : 1.0f;  // log2(e)/32
        #pragma unroll
        for (int mi = 0; mi < 4; ++mi)
            #pragma unroll
            for (int ni = 0; ni < 4; ++ni) {
                float bv = bias[colBase + wn + ni * 16 + l15];
                #pragma unroll
                for (int r = 0; r < 4; ++r) {
                    int m = wm + mi * 16 + quad * 4 + r;
                    int n = wn + ni * 16 + l15;
                    lds[m * 136 + n] = f2bf((acc[mi][ni][r] + bv) * qs);
                }
            }
        __syncthreads();
        unsigned short* dst = (s == 0) ? qB : kB;
        #pragma unroll
        for (int it = 0; it < 8; ++it) {
            int cc = tid + it * 256;
            int m = cc >> 4, j = cc & 15;
            uint4 v = *(const uint4*)(lds + m * 136 + j * 8);
            int hh = j >> 3, d0 = (j & 7) * 8;
            *(uint4*)(dst + ((size_t)(bh0 + hh) * Tv + tloc + m) * HDv + d0) = v;
        }
    } else {
        #pragma unroll
        for (int mi = 0; mi < 4; ++mi)
            #pragma unroll
            for (int ni = 0; ni < 4; ++ni) {
                float bv = bias[colBase + wn + ni * 16 + l15];
                #pragma unroll
                for (int r = 0; r < 4; ++r) {
                    int m = wm + mi * 16 + quad * 4 + r;
                    int n = wn + ni * 16 + l15;
                    lds[n * 136 + m] = f2bf(acc[mi][ni][r] + bv);
                }
            }
        __syncthreads();
        #pragma unroll
        for (int it = 0; it < 8; ++it) {
            int cc = tid + it * 256;
            int n = cc >> 4, j = cc & 15;
            uint4 v = *(const uint4*)(lds + n * 136 + j * 8);
            int hh = n >> 6, d = n & 63;
            *(uint4*)(vT + ((size_t)(bh0 + hh) * HDv + d) * Tv + tloc + j * 8) = v;
        }
    }
}

// ---------------------------------------------------------------------------
// Projection GEMM: bf16 MFMA, fp32 output + bias.
// ---------------------------------------------------------------------------
__global__ __launch_bounds__(256) void proj_mm_kernel(
    const unsigned short* __restrict__ y0B, const unsigned short* __restrict__ WpT,
    const float* __restrict__ bias, float* __restrict__ out)
{
    __shared__ __align__(16) unsigned short lds[24576];  // 48 KB staging
    const int rowBase = blockIdx.y * 128;
    const int colBase = blockIdx.x * 128;

    f32x4 acc[4][4];
    #pragma unroll
    for (int i = 0; i < 4; ++i)
        #pragma unroll
        for (int j = 0; j < 4; ++j) acc[i][j] = (f32x4){0.f, 0.f, 0.f, 0.f};

    mm_mainloop_1024(y0B, WpT, lds, rowBase, colBase, acc);

    const int tid = threadIdx.x, lane = tid & 63, w = tid >> 6;
    const int quad = lane >> 4, l15 = lane & 15;
    const int wm = (w >> 1) * 64, wn = (w & 1) * 64;

    #pragma unroll
    for (int mi = 0; mi < 4; ++mi)
        #pragma unroll
        for (int ni = 0; ni < 4; ++ni) {
            int n = colBase + wn + ni * 16 + l15;
            float bv = bias[n];
            #pragma unroll
            for (int r = 0; r < 4; ++r) {
                int m = rowBase + wm + mi * 16 + quad * 4 + r;
                out[(size_t)m * Cv + n] = acc[mi][ni][r] + bv;
            }
        }
}

// ---------------------------------------------------------------------------
// Causal attention, R9: back to R7 64-q-row / 4-wave / 1024-block structure
// (R8's 128-row tile halved co-residency -> regression), PLUS P/PV software
// pipeline: iter kt writes P(kt) to phase kt&1 with NO wait; PV(kt-1) runs
// at the top of iter kt reading phase (kt-1)&1 — the P write->read LDS
// latency hides under a full iteration. V(kt-1) frags carried in registers.
// lgkm in-order completion makes the cross-iter P dependency safe (the K/V
// frag-read waits of iter kt drain the P(kt-1) writes first).
// ---------------------------------------------------------------------------
__global__ __launch_bounds__(256, 3) void attn_kernel(
    const unsigned short* __restrict__ qB, const unsigned short* __restrict__ kB,
    const unsigned short* __restrict__ vT, unsigned short* __restrict__ y0B)
{
    // kv per buffer (8192 shorts): K tile [0,4096), V tile [4096,8192).
    __shared__ __align__(16) unsigned short kv[2 * 8192];       // 32 KB
    __shared__ __align__(16) unsigned short Pb[2][4][16 * 72];  // 18 KB (2 phases)

    const int tid  = threadIdx.x;
    const int lane = tid & 63;
    const int w    = tid >> 6;
    const int quad = lane >> 4;
    const int l15  = lane & 15;

    const int qt = 31 - (blockIdx.x >> 5);   // heavy tiles dispatch first
    const int bh = blockIdx.x & 31;
    const int qwbase = qt * 64 + w * 16;

    const unsigned short* qrow = qB + ((size_t)bh * Tv + qwbase + l15) * HDv;
    const bf16x8 Qa0 = *(const bf16x8*)(qrow + quad * 8);
    const bf16x8 Qa1 = *(const bf16x8*)(qrow + 32 + quad * 8);
    WAITVM(0);   // Q in regs; loop-local vmcnt tracks only staging GLDs

    f32x4 O[4];
    float l[4] = {0.f, 0.f, 0.f, 0.f};
    #pragma unroll
    for (int n = 0; n < 4; ++n) O[n] = (f32x4){0.f, 0.f, 0.f, 0.f};

    const unsigned short* Kbase = kB + (size_t)bh * Tv * HDv;
    const unsigned short* Vbase = vT + (size_t)bh * HDv * Tv;
    unsigned short* Pw0 = &Pb[0][w][0];
    unsigned short* Pw1 = &Pb[1][w][0];

    // Staging: thread covers 4 granule-slots/tile: K slots tid+{0,256},
    // V slots tid+{0,256}. Swizzles: K g^((row>>2)&7), V g^(d&7).
    const unsigned short* gK[2]; unsigned short* dK[2];
    const unsigned short* gV[2]; unsigned short* dV[2];
    #pragma unroll
    for (int i = 0; i < 2; ++i) {
        int slot = tid + i * 256;
        int row = slot >> 3;
        int gk = (slot & 7) ^ ((row >> 2) & 7);
        gK[i] = Kbase + row * HDv + gk * 8;
        dK[i] = kv + (size_t)(i * 256 + w * 64) * 8;
        int d = slot >> 3;
        int gv = (slot & 7) ^ (d & 7);
        gV[i] = Vbase + (size_t)d * Tv + gv * 8;
        dV[i] = kv + 4096 + (size_t)(i * 256 + w * 64) * 8;
    }

    // Fragment LDS short-offsets (constant across kt; add buffer offset).
    int koff[4][2], voff[4][2];
    #pragma unroll
    for (int ct = 0; ct < 4; ++ct) {
        int row = ct + 4 * l15;
        #pragma unroll
        for (int j = 0; j < 2; ++j)
            koff[ct][j] = (row * 8 + ((quad + 4 * j) ^ (l15 & 7))) * 8;
    }
    #pragma unroll
    for (int nt = 0; nt < 4; ++nt) {
        int d = nt * 16 + l15;
        #pragma unroll
        for (int j = 0; j < 2; ++j)
            voff[nt][j] = 4096 + (d * 8 + ((quad + 4 * j) ^ (l15 & 7))) * 8;
    }

    // Prologue: tile 0 into buf0.
    GLD16(gK[0], dK[0]);
    GLD16(gK[1], dK[1]);
    GLD16(gV[0], dV[0]);
    GLD16(gV[1], dV[1]);

    bf16x8 Vprev[4][2];
    int cur = 0;
    for (int kt = 0; kt <= qt; ++kt) {
        WAITVM(0);
        BARRIER;
        if (kt < qt) {
            const int kb1 = (kt + 1) * 64;
            const int nxt = 8192 - cur;
            GLD16(gK[0] + (size_t)kb1 * HDv, dK[0] + nxt);
            GLD16(gK[1] + (size_t)kb1 * HDv, dK[1] + nxt);
            GLD16(gV[0] + kb1, dV[0] + nxt);
            GLD16(gV[1] + kb1, dV[1] + nxt);
        }

        unsigned short* PwW = (kt & 1) ? Pw1 : Pw0;   // write phase (this tile)
        unsigned short* PwR = (kt & 1) ? Pw0 : Pw1;   // read phase (prev tile)

        // Deferred PV for tile kt-1 (P write latency hidden by one full iter)
        if (kt > 0) {
            const bf16x8 Pa0 = *(const bf16x8*)(PwR + l15 * 72 + quad * 8);
            const bf16x8 Pa1 = *(const bf16x8*)(PwR + l15 * 72 + 32 + quad * 8);
            #pragma unroll
            for (int nt = 0; nt < 4; ++nt) {
                O[nt] = __builtin_amdgcn_mfma_f32_16x16x32_bf16(Pa0, Vprev[nt][0], O[nt], 0, 0, 0);
                O[nt] = __builtin_amdgcn_mfma_f32_16x16x32_bf16(Pa1, Vprev[nt][1], O[nt], 0, 0, 0);
            }
        }

        // K frags + S MFMA for tile kt
        bf16x8 Kb[4][2];
        #pragma unroll
        for (int ct = 0; ct < 4; ++ct) {
            Kb[ct][0] = *(const bf16x8*)(kv + cur + koff[ct][0]);
            Kb[ct][1] = *(const bf16x8*)(kv + cur + koff[ct][1]);
        }
        f32x4 S[4];
        #pragma unroll
        for (int ct = 0; ct < 4; ++ct) {
            S[ct] = (f32x4){0.f, 0.f, 0.f, 0.f};
            S[ct] = __builtin_amdgcn_mfma_f32_16x16x32_bf16(Qa0, Kb[ct][0], S[ct], 0, 0, 0);
            S[ct] = __builtin_amdgcn_mfma_f32_16x16x32_bf16(Qa1, Kb[ct][1], S[ct], 0, 0, 0);
        }

        // V frags for tile kt (consumed by PV at iter kt+1 / epilogue)
        #pragma unroll
        for (int nt = 0; nt < 4; ++nt) {
            Vprev[nt][0] = *(const bf16x8*)(kv + cur + voff[nt][0]);
            Vprev[nt][1] = *(const bf16x8*)(kv + cur + voff[nt][1]);
        }

        if (kt == qt) {  // diagonal tile: mask key > q
            #pragma unroll
            for (int ct = 0; ct < 4; ++ct)
                #pragma unroll
                for (int r = 0; r < 4; ++r)
                    if (ct + 4 * l15 > w * 16 + quad * 4 + r) S[ct][r] = -1e30f;
        }

        float p[4][4];
        #pragma unroll
        for (int ct = 0; ct < 4; ++ct)
            #pragma unroll
            for (int r = 0; r < 4; ++r)
                p[ct][r] = __builtin_amdgcn_exp2f(S[ct][r]);
        #pragma unroll
        for (int r = 0; r < 4; ++r)
            l[r] += (p[0][r] + p[1][r]) + (p[2][r] + p[3][r]);

        // P pack into write phase; NO wait — read happens next iteration.
        #pragma unroll
        for (int r = 0; r < 4; ++r) {
            uint2 u = make_uint2(f2bf2(p[0][r], p[1][r]), f2bf2(p[2][r], p[3][r]));
            *(uint2*)(PwW + (quad * 4 + r) * 72 + l15 * 4) = u;
        }

        cur = 8192 - cur;
    }

    // Epilogue PV for the final tile qt (phase qt&1).
    {
        unsigned short* PwR = (qt & 1) ? Pw1 : Pw0;
        const bf16x8 Pa0 = *(const bf16x8*)(PwR + l15 * 72 + quad * 8);
        const bf16x8 Pa1 = *(const bf16x8*)(PwR + l15 * 72 + 32 + quad * 8);
        #pragma unroll
        for (int nt = 0; nt < 4; ++nt) {
            O[nt] = __builtin_amdgcn_mfma_f32_16x16x32_bf16(Pa0, Vprev[nt][0], O[nt], 0, 0, 0);
            O[nt] = __builtin_amdgcn_mfma_f32_16x16x32_bf16(Pa1, Vprev[nt][1], O[nt], 0, 0, 0);
        }
    }

    // One-time row-sum reduce across the 16 lanes holding each row's keys
    #pragma unroll
    for (int r = 0; r < 4; ++r) {
        l[r] += __shfl_xor(l[r], 1);
        l[r] += __shfl_xor(l[r], 2);
        l[r] += __shfl_xor(l[r], 4);
        l[r] += __shfl_xor(l[r], 8);
    }

    const int b = bh >> 4, h = bh & 15;
    #pragma unroll
    for (int r = 0; r < 4; ++r) {
        float inv = 1.f / l[r];
        int q = qwbase + quad * 4 + r;
        unsigned short* dst = y0B + ((size_t)(b * Tv + q)) * Cv + h * HDv + l15;
        #pragma unroll
        for (int n = 0; n < 4; ++n) dst[n * 16] = f2bf(O[n][r] * inv);
    }
}

// ---------------------------------------------------------------------------
// Workspace: xB 8MB | WaT 6MB | WpT 2MB | qB,kB,vT 24MB | y0B 8MB (~48 MB).
// ---------------------------------------------------------------------------
extern "C" void kernel_launch(void* const* d_in, const int* in_sizes, int n_in,
                              void* d_out, int out_size, void* d_ws, size_t ws_size,
                              hipStream_t stream) {
    const float* x      = (const float*)d_in[0];
    const float* W_attn = (const float*)d_in[1];
    const float* b_attn = (const float*)d_in[2];
    const float* W_proj = (const float*)d_in[3];
    const float* b_proj = (const float*)d_in[4];
    float* out = (float*)d_out;

    unsigned short* xB  = (unsigned short*)d_ws;
    unsigned short* WaT = xB  + (size_t)Mv * Cv;
    unsigned short* WpT = WaT + (size_t)3 * Cv * Cv;
    unsigned short* qB  = WpT + (size_t)Cv * Cv;
    unsigned short* kB  = qB + (size_t)SZv;
    unsigned short* vT  = kB + (size_t)SZv;
    unsigned short* y0B = vT + (size_t)SZv;

    dim3 blk(256);
    prep_kernel<<<dim3(8192), blk, 0, stream>>>(x, W_attn, W_proj, xB, WaT, WpT);
    qkv_mm_kernel<<<dim3(3 * Cv / 128, Mv / 128), blk, 0, stream>>>(xB, WaT, b_attn, qB, kB, vT);
    attn_kernel<<<dim3(Bv * Hv * (Tv / 64)), blk, 0, stream>>>(qB, kB, vT, y0B);
    proj_mm_kernel<<<dim3(Cv / 128, Mv / 128), blk, 0, stream>>>(y0B, WpT, b_proj, out);
}